// Round 1
// baseline (3817.745 us; speedup 1.0000x reference)
//
#include <hip/hip_runtime.h>
#include <math.h>

#define NN 50000
#define NE 800000
#define NG 64

// ---- order-preserving float<->uint encoding for atomicMax on f32 ----
__device__ __forceinline__ unsigned fenc(float x) {
  unsigned u = __float_as_uint(x);
  return (u & 0x80000000u) ? ~u : (u | 0x80000000u);
}
__device__ __forceinline__ float fdec(unsigned u) {
  return __uint_as_float((u & 0x80000000u) ? (u ^ 0x80000000u) : ~u);
}

// ---- kernel 1: per-edge spherical harmonics scatter + degrees ----
__global__ void k_sh_scatter(const float* __restrict__ vec,
                             const int* __restrict__ esrc,
                             const int* __restrict__ edst,
                             float* __restrict__ node_sh,
                             float* __restrict__ deg_in,
                             float* __restrict__ outdeg,
                             int E)
{
  int e = blockIdx.x * blockDim.x + threadIdx.x;
  if (e >= E) return;
  float vx = vec[3*e+0], vy = vec[3*e+1], vz = vec[3*e+2];
  float r = sqrtf(vx*vx + vy*vy + vz*vz + 1e-12f);
  float x = vx / r, y = vy / r, z = vz / r;
  const float s3  = 1.7320508075688772f;
  const float s15 = 3.872983346207417f;
  const float s5  = 2.23606797749979f;
  float sh[9];
  sh[0] = 1.f;
  sh[1] = s3*x; sh[2] = s3*y; sh[3] = s3*z;
  sh[4] = s15*x*z;
  sh[5] = s15*x*y;
  sh[6] = s5*(y*y - 0.5f*(x*x + z*z));
  sh[7] = s15*y*z;
  sh[8] = 0.5f*s15*(z*z - x*x);
  int d = edst[e];
  float* p = node_sh + (size_t)d*9;
  #pragma unroll
  for (int j = 0; j < 9; ++j) atomicAdd(p + j, sh[j]);
  atomicAdd(deg_in + d, 1.f);
  atomicAdd(outdeg + esrc[e], 1.f);
}

// ---- kernel 2: build initial node features [s(10), v(1x3), d(1x5)] ----
__global__ void k_init_svd0(const float* __restrict__ xs,
                            const float* __restrict__ node_sh,
                            const float* __restrict__ deg_in,
                            float* __restrict__ svd0, int N)
{
  int n = blockIdx.x*blockDim.x + threadIdx.x;
  if (n >= N) return;
  float inv = 1.f / fmaxf(deg_in[n], 1.f);
  float* o = svd0 + (size_t)n*18;
  const float* xrow = xs + (size_t)n*9;
  #pragma unroll
  for (int j = 0; j < 9; ++j) o[j] = xrow[j];
  const float* s = node_sh + (size_t)n*9;
  #pragma unroll
  for (int j = 0; j < 9; ++j) o[9+j] = s[j]*inv;
}

// ---- kernel A: node-level q/k/v features; q is pre-contracted with Wd ----
// in layout per node: [s(CS), v(CV*3 as i*3+m), d(CV*5 as i*5+m)]
// out layouts (72 floats): [c(8)] [8 + c*3+m] [32 + c*5+m]
template<int CS, int CV>
__global__ void __launch_bounds__(256) k_node_feats(
    const float* __restrict__ in,
    const float* __restrict__ W0,  // [3,CS,8]
    const float* __restrict__ W1,  // [3,CV,8]
    const float* __restrict__ W2,  // [3,CV,8]
    const float* __restrict__ Wd,  // [3,8,8]
    float* __restrict__ qt,
    float* __restrict__ kf,
    float* __restrict__ vf,
    int N)
{
  int n = blockIdx.x*blockDim.x + threadIdx.x;
  if (n >= N) return;
  const float* x = in + (size_t)n*(CS + 8*CV);
  float s_in[CS];
  float v_in[CV][3];
  float d_in[CV][5];
  #pragma unroll
  for (int i = 0; i < CS; ++i) s_in[i] = x[i];
  #pragma unroll
  for (int i = 0; i < CV; ++i)
    #pragma unroll
    for (int m = 0; m < 3; ++m) v_in[i][m] = x[CS + i*3 + m];
  #pragma unroll
  for (int i = 0; i < CV; ++i)
    #pragma unroll
    for (int m = 0; m < 5; ++m) d_in[i][m] = x[CS + 3*CV + i*5 + m];

  const float inv_s3 = 0.5773502691896258f;   // 1/sqrt(3)
  const float inv_s5 = 0.4472135954999579f;   // 1/sqrt(5)

  #pragma unroll
  for (int t = 0; t < 3; ++t) {
    float ss[8];
    float vv[8][3];
    float dd[8][5];
    #pragma unroll
    for (int c = 0; c < 8; ++c) {
      float a = 0.f;
      #pragma unroll
      for (int i = 0; i < CS; ++i) a += s_in[i]*W0[t*CS*8 + i*8 + c];
      ss[c] = a;
    }
    #pragma unroll
    for (int c = 0; c < 8; ++c)
      #pragma unroll
      for (int m = 0; m < 3; ++m) {
        float a = 0.f;
        #pragma unroll
        for (int i = 0; i < CV; ++i) a += v_in[i][m]*W1[t*CV*8 + i*8 + c];
        vv[c][m] = a;
      }
    #pragma unroll
    for (int c = 0; c < 8; ++c)
      #pragma unroll
      for (int m = 0; m < 5; ++m) {
        float a = 0.f;
        #pragma unroll
        for (int i = 0; i < CV; ++i) a += d_in[i][m]*W2[t*CV*8 + i*8 + c];
        dd[c][m] = a;
      }

    if (t == 0) {
      float* q = qt + (size_t)n*72;
      #pragma unroll
      for (int dp = 0; dp < 8; ++dp) {
        float a = 0.f;
        #pragma unroll
        for (int c = 0; c < 8; ++c) a += ss[c]*Wd[0*64 + c*8 + dp];
        q[dp] = a;
      }
      #pragma unroll
      for (int dp = 0; dp < 8; ++dp)
        #pragma unroll
        for (int m = 0; m < 3; ++m) {
          float a = 0.f;
          #pragma unroll
          for (int c = 0; c < 8; ++c) a += vv[c][m]*Wd[1*64 + c*8 + dp];
          q[8 + dp*3 + m] = a*inv_s3;
        }
      #pragma unroll
      for (int dp = 0; dp < 8; ++dp)
        #pragma unroll
        for (int m = 0; m < 5; ++m) {
          float a = 0.f;
          #pragma unroll
          for (int c = 0; c < 8; ++c) a += dd[c][m]*Wd[2*64 + c*8 + dp];
          q[32 + dp*5 + m] = a*inv_s5;
        }
    } else {
      float* o = (t == 1 ? kf : vf) + (size_t)n*72;
      #pragma unroll
      for (int c = 0; c < 8; ++c) o[c] = ss[c];
      #pragma unroll
      for (int c = 0; c < 8; ++c)
        #pragma unroll
        for (int m = 0; m < 3; ++m) o[8 + c*3 + m] = vv[c][m];
      #pragma unroll
      for (int c = 0; c < 8; ++c)
        #pragma unroll
        for (int m = 0; m < 5; ++m) o[32 + c*5 + m] = dd[c][m];
    }
  }
}

// ---- kernel B: per-edge logit = dot72(qt[dst], kf[src]); segmented max ----
__global__ void k_edge_logit(const float* __restrict__ qt,
                             const float* __restrict__ kf,
                             const int* __restrict__ esrc,
                             const int* __restrict__ edst,
                             float* __restrict__ elog,
                             unsigned* __restrict__ mx,
                             int E)
{
  int e = blockIdx.x*blockDim.x + threadIdx.x;
  if (e >= E) return;
  int s = esrc[e], d = edst[e];
  const float4* qa = (const float4*)(qt + (size_t)d*72);
  const float4* kb = (const float4*)(kf + (size_t)s*72);
  float acc = 0.f;
  #pragma unroll
  for (int j = 0; j < 18; ++j) {
    float4 a = qa[j], b = kb[j];
    acc += a.x*b.x + a.y*b.y + a.z*b.z + a.w*b.w;
  }
  elog[e] = acc;
  atomicMax(mx + d, fenc(acc));
}

// ---- kernel C: expv = exp(logit - max[dst]); z[dst] += expv ----
__global__ void k_edge_exp(float* __restrict__ elog,
                           const unsigned* __restrict__ mx,
                           const int* __restrict__ edst,
                           float* __restrict__ z, int E)
{
  int e = blockIdx.x*blockDim.x + threadIdx.x;
  if (e >= E) return;
  int d = edst[e];
  float ev = expf(elog[e] - fdec(mx[d]));
  elog[e] = ev;
  atomicAdd(z + d, ev);
}

// ---- kernel D: out[dst] += sqrt(ev/z[dst]) * vf[src]  (18 float4 / edge) ----
__global__ void k_edge_scatter(const float* __restrict__ ev,
                               const float* __restrict__ z,
                               const float* __restrict__ vf,
                               const int* __restrict__ esrc,
                               const int* __restrict__ edst,
                               float* __restrict__ out, int E)
{
  int tid = blockIdx.x*blockDim.x + threadIdx.x;
  int e = tid / 18, j = tid % 18;
  if (e >= E) return;
  int d = edst[e];
  float w = sqrtf(ev[e] / z[d]);
  float4 v = *(const float4*)(vf + (size_t)esrc[e]*72 + j*4);
  float* o = out + (size_t)d*72 + j*4;
  atomicAdd(o + 0, w*v.x);
  atomicAdd(o + 1, w*v.y);
  atomicAdd(o + 2, w*v.z);
  atomicAdd(o + 3, w*v.w);
}

// ---- fused head: h=relu(L2norm(s@Wol)); 2x relu(h@W+b); group pooling ----
// block = 128 threads handles 16 consecutive nodes (N divisible by 16)
__global__ void __launch_bounds__(128) k_head(
    const float* __restrict__ svd,   // [N,72], s = first 8
    const float* __restrict__ Wol,   // [8,128]
    const float* __restrict__ Wlin,  // [2,128,128]
    const float* __restrict__ blin,  // [2,128]
    const float* __restrict__ outdeg,
    const int* __restrict__ bseg,
    float* __restrict__ m,           // [G,128] atomic
    float* __restrict__ cg,          // [G] atomic
    int N)
{
  __shared__ float hs[16][128];
  __shared__ float ssm[16][8];
  __shared__ float nrm[16];
  int c = threadIdx.x;
  int n0 = blockIdx.x*16;

  { // cooperative load of 16 nodes x 8 scalars
    int nn = c >> 3, i = c & 7;
    ssm[nn][i] = svd[(size_t)(n0+nn)*72 + i];
  }
  __syncthreads();

  float acc[16];
  #pragma unroll
  for (int nn = 0; nn < 16; ++nn) acc[nn] = 0.f;
  #pragma unroll
  for (int i = 0; i < 8; ++i) {
    float w = Wol[i*128 + c];
    #pragma unroll
    for (int nn = 0; nn < 16; ++nn) acc[nn] += ssm[nn][i]*w;
  }
  #pragma unroll
  for (int nn = 0; nn < 16; ++nn) hs[nn][c] = acc[nn];
  __syncthreads();
  if (c < 16) {
    float sq = 0.f;
    for (int i = 0; i < 128; ++i) { float h = hs[c][i]; sq += h*h; }
    nrm[c] = fmaxf(sqrtf(sq), 1e-12f);
  }
  __syncthreads();
  #pragma unroll
  for (int nn = 0; nn < 16; ++nn)
    hs[nn][c] = fmaxf(hs[nn][c] / nrm[nn], 0.f);
  __syncthreads();

  for (int l = 0; l < 2; ++l) {
    float b = blin[l*128 + c];
    float a2[16];
    #pragma unroll
    for (int nn = 0; nn < 16; ++nn) a2[nn] = b;
    for (int i = 0; i < 128; ++i) {
      float w = Wlin[l*16384 + i*128 + c];
      #pragma unroll
      for (int nn = 0; nn < 16; ++nn) a2[nn] += hs[nn][i]*w;
    }
    __syncthreads();
    #pragma unroll
    for (int nn = 0; nn < 16; ++nn) hs[nn][c] = fmaxf(a2[nn], 0.f);
    __syncthreads();
  }

  // group pooling: m[g] += outdeg[n]*h[n]; bseg is sorted -> few flushes
  float accm = 0.f; int gprev = -1;
  for (int nn = 0; nn < 16; ++nn) {
    int n = n0 + nn;
    int g = bseg[n];
    if (g != gprev) {
      if (gprev >= 0) atomicAdd(&m[gprev*128 + c], accm);
      accm = 0.f; gprev = g;
    }
    accm += outdeg[n]*hs[nn][c];
  }
  if (gprev >= 0) atomicAdd(&m[gprev*128 + c], accm);

  if (c == 0) {
    float a = 0.f; int gp = -1;
    for (int nn = 0; nn < 16; ++nn) {
      int n = n0 + nn;
      int g = bseg[n];
      if (g != gp) {
        if (gp >= 0) atomicAdd(&cg[gp], a);
        a = 0.f; gp = g;
      }
      a += outdeg[n];
    }
    if (gp >= 0) atomicAdd(&cg[gp], a);
  }
}

// ---- final: softmax((m/cg) @ Wout + bout) ----
__global__ void k_out(const float* __restrict__ m, const float* __restrict__ cg,
                      const float* __restrict__ Wout, const float* __restrict__ bout,
                      float* __restrict__ out)
{
  int g = threadIdx.x;
  if (g >= NG) return;
  float inv = 1.f / fmaxf(cg[g], 1.f);
  float v[9];
  #pragma unroll
  for (int j = 0; j < 9; ++j) {
    float a = 0.f;
    for (int i = 0; i < 128; ++i) a += m[g*128 + i]*Wout[i*9 + j];
    v[j] = a*inv + bout[j];
  }
  float mxv = v[0];
  #pragma unroll
  for (int j = 1; j < 9; ++j) mxv = fmaxf(mxv, v[j]);
  float sum = 0.f;
  #pragma unroll
  for (int j = 0; j < 9; ++j) { v[j] = expf(v[j] - mxv); sum += v[j]; }
  #pragma unroll
  for (int j = 0; j < 9; ++j) out[g*9 + j] = v[j]/sum;
}

extern "C" void kernel_launch(void* const* d_in, const int* in_sizes, int n_in,
                              void* d_out, int out_size, void* d_ws, size_t ws_size,
                              hipStream_t stream) {
  (void)in_sizes; (void)n_in; (void)out_size; (void)ws_size;
  const float* x_scalars = (const float*)d_in[0];
  const float* edge_vec  = (const float*)d_in[1];
  const float* et0_W0    = (const float*)d_in[2];
  const float* et0_W1    = (const float*)d_in[3];
  const float* et0_W2    = (const float*)d_in[4];
  const float* et0_Wd    = (const float*)d_in[5];
  const float* h_W0      = (const float*)d_in[6];
  const float* h_W1      = (const float*)d_in[7];
  const float* h_W2      = (const float*)d_in[8];
  const float* h_Wd      = (const float*)d_in[9];
  const float* Wol       = (const float*)d_in[10];
  const float* Wlin      = (const float*)d_in[11];
  const float* blin      = (const float*)d_in[12];
  const float* Wout      = (const float*)d_in[13];
  const float* bout      = (const float*)d_in[14];
  const int*   esrc      = (const int*)d_in[15];
  const int*   edst      = (const int*)d_in[16];
  const int*   bseg      = (const int*)d_in[17];

  const int N = NN, E = NE;

  char* w = (char*)d_ws;
  auto alloc = [&](size_t nbytes) {
    char* p = w;
    w += (nbytes + 255) & ~(size_t)255;
    return p;
  };
  float*    node_sh = (float*)   alloc((size_t)N*9*4);
  float*    deg_in  = (float*)   alloc((size_t)N*4);
  float*    outdeg  = (float*)   alloc((size_t)N*4);
  float*    svd0    = (float*)   alloc((size_t)N*18*4);
  float*    stA     = (float*)   alloc((size_t)N*72*4);
  float*    stB     = (float*)   alloc((size_t)N*72*4);
  float*    qt      = (float*)   alloc((size_t)N*72*4);
  float*    kf      = (float*)   alloc((size_t)N*72*4);
  float*    vf      = (float*)   alloc((size_t)N*72*4);
  float*    elog    = (float*)   alloc((size_t)E*4);
  float*    zbuf    = (float*)   alloc((size_t)N*4);
  unsigned* mxb     = (unsigned*)alloc((size_t)N*4);
  float*    mpool   = (float*)   alloc((size_t)NG*128*4);
  float*    cgp     = (float*)   alloc((size_t)NG*4);

  hipMemsetAsync(node_sh, 0, (size_t)N*9*4, stream);
  hipMemsetAsync(deg_in,  0, (size_t)N*4, stream);
  hipMemsetAsync(outdeg,  0, (size_t)N*4, stream);
  hipMemsetAsync(mpool,   0, (size_t)NG*128*4, stream);
  hipMemsetAsync(cgp,     0, (size_t)NG*4, stream);

  const int TB = 256;
  const int gE  = (E + TB - 1) / TB;
  const int gN  = (N + TB - 1) / TB;
  const int gE18 = (E*18 + TB - 1) / TB;

  k_sh_scatter<<<gE, TB, 0, stream>>>(edge_vec, esrc, edst, node_sh, deg_in, outdeg, E);
  k_init_svd0<<<gN, TB, 0, stream>>>(x_scalars, node_sh, deg_in, svd0, N);

  // ---- et0 layer (no residual): input stride 18, CS=10, CV=1 ----
  hipMemsetAsync(stA, 0, (size_t)N*72*4, stream);
  hipMemsetAsync(zbuf, 0, (size_t)N*4, stream);
  hipMemsetAsync(mxb, 0, (size_t)N*4, stream);
  k_node_feats<10,1><<<gN, TB, 0, stream>>>(svd0, et0_W0, et0_W1, et0_W2, et0_Wd, qt, kf, vf, N);
  k_edge_logit<<<gE, TB, 0, stream>>>(qt, kf, esrc, edst, elog, mxb, E);
  k_edge_exp<<<gE, TB, 0, stream>>>(elog, mxb, edst, zbuf, E);
  k_edge_scatter<<<gE18, TB, 0, stream>>>(elog, zbuf, vf, esrc, edst, stA, E);

  // ---- 2 hidden layers with residual ----
  float* cur = stA; float* oth = stB;
  for (int l = 0; l < 2; ++l) {
    hipMemcpyAsync(oth, cur, (size_t)N*72*4, hipMemcpyDeviceToDevice, stream);
    hipMemsetAsync(zbuf, 0, (size_t)N*4, stream);
    hipMemsetAsync(mxb, 0, (size_t)N*4, stream);
    k_node_feats<8,8><<<gN, TB, 0, stream>>>(cur, h_W0 + l*192, h_W1 + l*192,
                                             h_W2 + l*192, h_Wd + l*192, qt, kf, vf, N);
    k_edge_logit<<<gE, TB, 0, stream>>>(qt, kf, esrc, edst, elog, mxb, E);
    k_edge_exp<<<gE, TB, 0, stream>>>(elog, mxb, edst, zbuf, E);
    k_edge_scatter<<<gE18, TB, 0, stream>>>(elog, zbuf, vf, esrc, edst, oth, E);
    float* t = cur; cur = oth; oth = t;
  }

  // ---- fused MLP head + group pooling ----
  k_head<<<N/16, 128, 0, stream>>>(cur, Wol, Wlin, blin, outdeg, bseg, mpool, cgp, N);
  k_out<<<1, 64, 0, stream>>>(mpool, cgp, Wout, bout, (float*)d_out);
}

// Round 2
// 1169.734 us; speedup vs baseline: 3.2638x; 3.2638x over previous
//
#include <hip/hip_runtime.h>
#include <math.h>

#define NN 50000
#define NE 800000
#define NG 64

// ---- kernel 1: per-edge spherical harmonics scatter (9 atomics/edge) ----
__global__ void k_sh_scatter(const float* __restrict__ vec,
                             const int* __restrict__ edst,
                             float* __restrict__ node_sh,
                             int E)
{
  int e = blockIdx.x * blockDim.x + threadIdx.x;
  if (e >= E) return;
  float vx = vec[3*e+0], vy = vec[3*e+1], vz = vec[3*e+2];
  float r = sqrtf(vx*vx + vy*vy + vz*vz + 1e-12f);
  float x = vx / r, y = vy / r, z = vz / r;
  const float s3  = 1.7320508075688772f;
  const float s15 = 3.872983346207417f;
  const float s5  = 2.23606797749979f;
  float sh[9];
  sh[0] = 1.f;
  sh[1] = s3*x; sh[2] = s3*y; sh[3] = s3*z;
  sh[4] = s15*x*z;
  sh[5] = s15*x*y;
  sh[6] = s5*(y*y - 0.5f*(x*x + z*z));
  sh[7] = s15*y*z;
  sh[8] = 0.5f*s15*(z*z - x*x);
  int d = edst[e];
  float* p = node_sh + (size_t)d*9;
  #pragma unroll
  for (int j = 0; j < 9; ++j) atomicAdd(p + j, sh[j]);
}

// ---- CSR build: count ----
__global__ void k_count(const int* __restrict__ esrc, const int* __restrict__ edst,
                        int* __restrict__ indeg, int* __restrict__ outdeg, int E)
{
  int e = blockIdx.x*blockDim.x + threadIdx.x;
  if (e >= E) return;
  atomicAdd(indeg + edst[e], 1);
  atomicAdd(outdeg + esrc[e], 1);
}

// ---- CSR build: single-block exclusive prefix scan over N=50000 ----
__global__ void __launch_bounds__(1024) k_prefix(const int* __restrict__ indeg,
                                                 int* __restrict__ rowptr, int N)
{
  __shared__ int tot[1024];
  int t = threadIdx.x;
  int chunk = (N + 1023) / 1024;
  int lo = t*chunk, hi = lo + chunk; if (hi > N) hi = N; if (lo > N) lo = N;
  int s = 0;
  for (int i = lo; i < hi; ++i) s += indeg[i];
  tot[t] = s;
  __syncthreads();
  for (int off = 1; off < 1024; off <<= 1) {
    int v = 0;
    if (t >= off) v = tot[t-off];
    __syncthreads();
    if (t >= off) tot[t] += v;
    __syncthreads();
  }
  int base = (t == 0) ? 0 : tot[t-1];
  for (int i = lo; i < hi; ++i) {
    rowptr[i] = base;
    base += indeg[i];
  }
  if (t == 1023) rowptr[N] = tot[1023];
}

// ---- CSR build: fill (slot order within a node is atomic-nondet; sums only) ----
__global__ void k_fill(const int* __restrict__ esrc, const int* __restrict__ edst,
                       const int* __restrict__ rowptr, int* __restrict__ cursor,
                       int* __restrict__ csr_src, int* __restrict__ csr_dst, int E)
{
  int e = blockIdx.x*blockDim.x + threadIdx.x;
  if (e >= E) return;
  int d = edst[e];
  int slot = rowptr[d] + atomicAdd(cursor + d, 1);
  csr_src[slot] = esrc[e];
  csr_dst[slot] = d;
}

// ---- kernel 2: build initial node features [s(10), v(1x3), d(1x5)] ----
__global__ void k_init_svd0(const float* __restrict__ xs,
                            const float* __restrict__ node_sh,
                            const int* __restrict__ indeg,
                            float* __restrict__ svd0, int N)
{
  int n = blockIdx.x*blockDim.x + threadIdx.x;
  if (n >= N) return;
  int dg = indeg[n];
  float inv = 1.f / (float)(dg > 1 ? dg : 1);
  float* o = svd0 + (size_t)n*18;
  const float* xrow = xs + (size_t)n*9;
  #pragma unroll
  for (int j = 0; j < 9; ++j) o[j] = xrow[j];
  const float* s = node_sh + (size_t)n*9;
  #pragma unroll
  for (int j = 0; j < 9; ++j) o[9+j] = s[j]*inv;
}

// ---- kernel A: node-level q/k/v features; q is pre-contracted with Wd ----
template<int CS, int CV>
__global__ void __launch_bounds__(256) k_node_feats(
    const float* __restrict__ in,
    const float* __restrict__ W0,  // [3,CS,8]
    const float* __restrict__ W1,  // [3,CV,8]
    const float* __restrict__ W2,  // [3,CV,8]
    const float* __restrict__ Wd,  // [3,8,8]
    float* __restrict__ qt,
    float* __restrict__ kf,
    float* __restrict__ vf,
    int N)
{
  int n = blockIdx.x*blockDim.x + threadIdx.x;
  if (n >= N) return;
  const float* x = in + (size_t)n*(CS + 8*CV);
  float s_in[CS];
  float v_in[CV][3];
  float d_in[CV][5];
  #pragma unroll
  for (int i = 0; i < CS; ++i) s_in[i] = x[i];
  #pragma unroll
  for (int i = 0; i < CV; ++i)
    #pragma unroll
    for (int m = 0; m < 3; ++m) v_in[i][m] = x[CS + i*3 + m];
  #pragma unroll
  for (int i = 0; i < CV; ++i)
    #pragma unroll
    for (int m = 0; m < 5; ++m) d_in[i][m] = x[CS + 3*CV + i*5 + m];

  const float inv_s3 = 0.5773502691896258f;
  const float inv_s5 = 0.4472135954999579f;

  #pragma unroll
  for (int t = 0; t < 3; ++t) {
    float ss[8];
    float vv[8][3];
    float dd[8][5];
    #pragma unroll
    for (int c = 0; c < 8; ++c) {
      float a = 0.f;
      #pragma unroll
      for (int i = 0; i < CS; ++i) a += s_in[i]*W0[t*CS*8 + i*8 + c];
      ss[c] = a;
    }
    #pragma unroll
    for (int c = 0; c < 8; ++c)
      #pragma unroll
      for (int m = 0; m < 3; ++m) {
        float a = 0.f;
        #pragma unroll
        for (int i = 0; i < CV; ++i) a += v_in[i][m]*W1[t*CV*8 + i*8 + c];
        vv[c][m] = a;
      }
    #pragma unroll
    for (int c = 0; c < 8; ++c)
      #pragma unroll
      for (int m = 0; m < 5; ++m) {
        float a = 0.f;
        #pragma unroll
        for (int i = 0; i < CV; ++i) a += d_in[i][m]*W2[t*CV*8 + i*8 + c];
        dd[c][m] = a;
      }

    if (t == 0) {
      float* q = qt + (size_t)n*72;
      #pragma unroll
      for (int dp = 0; dp < 8; ++dp) {
        float a = 0.f;
        #pragma unroll
        for (int c = 0; c < 8; ++c) a += ss[c]*Wd[0*64 + c*8 + dp];
        q[dp] = a;
      }
      #pragma unroll
      for (int dp = 0; dp < 8; ++dp)
        #pragma unroll
        for (int m = 0; m < 3; ++m) {
          float a = 0.f;
          #pragma unroll
          for (int c = 0; c < 8; ++c) a += vv[c][m]*Wd[1*64 + c*8 + dp];
          q[8 + dp*3 + m] = a*inv_s3;
        }
      #pragma unroll
      for (int dp = 0; dp < 8; ++dp)
        #pragma unroll
        for (int m = 0; m < 5; ++m) {
          float a = 0.f;
          #pragma unroll
          for (int c = 0; c < 8; ++c) a += dd[c][m]*Wd[2*64 + c*8 + dp];
          q[32 + dp*5 + m] = a*inv_s5;
        }
    } else {
      float* o = (t == 1 ? kf : vf) + (size_t)n*72;
      #pragma unroll
      for (int c = 0; c < 8; ++c) o[c] = ss[c];
      #pragma unroll
      for (int c = 0; c < 8; ++c)
        #pragma unroll
        for (int m = 0; m < 3; ++m) o[8 + c*3 + m] = vv[c][m];
      #pragma unroll
      for (int c = 0; c < 8; ++c)
        #pragma unroll
        for (int m = 0; m < 5; ++m) o[32 + c*5 + m] = dd[c][m];
    }
  }
}

// ---- kernel B: slot-parallel logit; dst-sorted so qt rows hit L1 ----
__global__ void k_edge_logit2(const float* __restrict__ qt,
                              const float* __restrict__ kf,
                              const int* __restrict__ csr_src,
                              const int* __restrict__ csr_dst,
                              float* __restrict__ elog, int E)
{
  int s = blockIdx.x*blockDim.x + threadIdx.x;
  if (s >= E) return;
  const float4* qa = (const float4*)(qt + (size_t)csr_dst[s]*72);
  const float4* kb = (const float4*)(kf + (size_t)csr_src[s]*72);
  float acc = 0.f;
  #pragma unroll
  for (int j = 0; j < 18; ++j) {
    float4 a = qa[j], b = kb[j];
    acc += a.x*b.x + a.y*b.y + a.z*b.z + a.w*b.w;
  }
  elog[s] = acc;
}

// ---- kernel D: per-node softmax + weighted gather, 18 threads/node ----
// block = 576 threads (9 waves) = 32 nodes
#define GA_NODES 32
__global__ void __launch_bounds__(576) k_attn_gather(
    const float* __restrict__ elog,
    const float* __restrict__ vf,
    const int* __restrict__ csr_src,
    const int* __restrict__ rowptr,
    const float* __restrict__ base,   // residual input or nullptr
    float* __restrict__ out, int N)
{
  int t = threadIdx.x;
  int n = blockIdx.x*GA_NODES + t/18;
  int j = t - (t/18)*18;
  if (n >= N) return;
  int b = rowptr[n], e2 = rowptr[n+1];
  float ax = 0.f, ay = 0.f, az = 0.f, aw = 0.f;
  if (e2 > b) {
    float mx = -3.4e38f;
    for (int s = b; s < e2; ++s) mx = fmaxf(mx, elog[s]);
    float sum = 0.f;
    for (int s = b; s < e2; ++s) sum += expf(elog[s] - mx);
    float inv = 1.f / sum;
    for (int s = b; s < e2; ++s) {
      float wv = sqrtf(expf(elog[s] - mx) * inv);
      const float4 v = *(const float4*)(vf + (size_t)csr_src[s]*72 + j*4);
      ax += wv*v.x; ay += wv*v.y; az += wv*v.z; aw += wv*v.w;
    }
  }
  if (base) {
    const float4 bb = *(const float4*)(base + (size_t)n*72 + j*4);
    ax += bb.x; ay += bb.y; az += bb.z; aw += bb.w;
  }
  float4 r; r.x = ax; r.y = ay; r.z = az; r.w = aw;
  *(float4*)(out + (size_t)n*72 + j*4) = r;
}

// ---- fused head: h=relu(L2norm(s@Wol)); 2x relu(h@W+b); group pooling ----
__global__ void __launch_bounds__(128) k_head(
    const float* __restrict__ svd,   // [N,72], s = first 8
    const float* __restrict__ Wol,   // [8,128]
    const float* __restrict__ Wlin,  // [2,128,128]
    const float* __restrict__ blin,  // [2,128]
    const int* __restrict__ outdeg,
    const int* __restrict__ bseg,
    float* __restrict__ m,           // [G,128] atomic
    float* __restrict__ cg,          // [G] atomic
    int N)
{
  __shared__ float hs[16][128];
  __shared__ float ssm[16][8];
  __shared__ float nrm[16];
  int c = threadIdx.x;
  int n0 = blockIdx.x*16;

  {
    int nn = c >> 3, i = c & 7;
    ssm[nn][i] = svd[(size_t)(n0+nn)*72 + i];
  }
  __syncthreads();

  float acc[16];
  #pragma unroll
  for (int nn = 0; nn < 16; ++nn) acc[nn] = 0.f;
  #pragma unroll
  for (int i = 0; i < 8; ++i) {
    float w = Wol[i*128 + c];
    #pragma unroll
    for (int nn = 0; nn < 16; ++nn) acc[nn] += ssm[nn][i]*w;
  }
  #pragma unroll
  for (int nn = 0; nn < 16; ++nn) hs[nn][c] = acc[nn];
  __syncthreads();
  if (c < 16) {
    float sq = 0.f;
    for (int i = 0; i < 128; ++i) { float h = hs[c][i]; sq += h*h; }
    nrm[c] = fmaxf(sqrtf(sq), 1e-12f);
  }
  __syncthreads();
  #pragma unroll
  for (int nn = 0; nn < 16; ++nn)
    hs[nn][c] = fmaxf(hs[nn][c] / nrm[nn], 0.f);
  __syncthreads();

  for (int l = 0; l < 2; ++l) {
    float b = blin[l*128 + c];
    float a2[16];
    #pragma unroll
    for (int nn = 0; nn < 16; ++nn) a2[nn] = b;
    for (int i = 0; i < 128; ++i) {
      float w = Wlin[l*16384 + i*128 + c];
      #pragma unroll
      for (int nn = 0; nn < 16; ++nn) a2[nn] += hs[nn][i]*w;
    }
    __syncthreads();
    #pragma unroll
    for (int nn = 0; nn < 16; ++nn) hs[nn][c] = fmaxf(a2[nn], 0.f);
    __syncthreads();
  }

  float accm = 0.f; int gprev = -1;
  for (int nn = 0; nn < 16; ++nn) {
    int n = n0 + nn;
    int g = bseg[n];
    if (g != gprev) {
      if (gprev >= 0) atomicAdd(&m[gprev*128 + c], accm);
      accm = 0.f; gprev = g;
    }
    accm += (float)outdeg[n]*hs[nn][c];
  }
  if (gprev >= 0) atomicAdd(&m[gprev*128 + c], accm);

  if (c == 0) {
    float a = 0.f; int gp = -1;
    for (int nn = 0; nn < 16; ++nn) {
      int n = n0 + nn;
      int g = bseg[n];
      if (g != gp) {
        if (gp >= 0) atomicAdd(&cg[gp], a);
        a = 0.f; gp = g;
      }
      a += (float)outdeg[n];
    }
    if (gp >= 0) atomicAdd(&cg[gp], a);
  }
}

// ---- final: softmax((m/cg) @ Wout + bout) ----
__global__ void k_out(const float* __restrict__ m, const float* __restrict__ cg,
                      const float* __restrict__ Wout, const float* __restrict__ bout,
                      float* __restrict__ out)
{
  int g = threadIdx.x;
  if (g >= NG) return;
  float inv = 1.f / fmaxf(cg[g], 1.f);
  float v[9];
  #pragma unroll
  for (int j = 0; j < 9; ++j) {
    float a = 0.f;
    for (int i = 0; i < 128; ++i) a += m[g*128 + i]*Wout[i*9 + j];
    v[j] = a*inv + bout[j];
  }
  float mxv = v[0];
  #pragma unroll
  for (int j = 1; j < 9; ++j) mxv = fmaxf(mxv, v[j]);
  float sum = 0.f;
  #pragma unroll
  for (int j = 0; j < 9; ++j) { v[j] = expf(v[j] - mxv); sum += v[j]; }
  #pragma unroll
  for (int j = 0; j < 9; ++j) out[g*9 + j] = v[j]/sum;
}

extern "C" void kernel_launch(void* const* d_in, const int* in_sizes, int n_in,
                              void* d_out, int out_size, void* d_ws, size_t ws_size,
                              hipStream_t stream) {
  (void)in_sizes; (void)n_in; (void)out_size; (void)ws_size;
  const float* x_scalars = (const float*)d_in[0];
  const float* edge_vec  = (const float*)d_in[1];
  const float* et0_W0    = (const float*)d_in[2];
  const float* et0_W1    = (const float*)d_in[3];
  const float* et0_W2    = (const float*)d_in[4];
  const float* et0_Wd    = (const float*)d_in[5];
  const float* h_W0      = (const float*)d_in[6];
  const float* h_W1      = (const float*)d_in[7];
  const float* h_W2      = (const float*)d_in[8];
  const float* h_Wd      = (const float*)d_in[9];
  const float* Wol       = (const float*)d_in[10];
  const float* Wlin      = (const float*)d_in[11];
  const float* blin      = (const float*)d_in[12];
  const float* Wout      = (const float*)d_in[13];
  const float* bout      = (const float*)d_in[14];
  const int*   esrc      = (const int*)d_in[15];
  const int*   edst      = (const int*)d_in[16];
  const int*   bseg      = (const int*)d_in[17];

  const int N = NN, E = NE;

  char* w = (char*)d_ws;
  auto alloc = [&](size_t nbytes) {
    char* p = w;
    w += (nbytes + 255) & ~(size_t)255;
    return p;
  };
  int*   indeg   = (int*)  alloc((size_t)N*4);
  int*   outdeg  = (int*)  alloc((size_t)N*4);
  int*   cursor  = (int*)  alloc((size_t)N*4);
  int*   rowptr  = (int*)  alloc((size_t)(N+1)*4);
  int*   csr_src = (int*)  alloc((size_t)E*4);
  int*   csr_dst = (int*)  alloc((size_t)E*4);
  float* node_sh = (float*)alloc((size_t)N*9*4);
  float* svd0    = (float*)alloc((size_t)N*18*4);
  float* stA     = (float*)alloc((size_t)N*72*4);
  float* stB     = (float*)alloc((size_t)N*72*4);
  float* qt      = (float*)alloc((size_t)N*72*4);
  float* kf      = (float*)alloc((size_t)N*72*4);
  float* vf      = (float*)alloc((size_t)N*72*4);
  float* elog    = (float*)alloc((size_t)E*4);
  float* mpool   = (float*)alloc((size_t)NG*128*4);
  float* cgp     = (float*)alloc((size_t)NG*4);

  hipMemsetAsync(indeg,   0, (size_t)N*4, stream);
  hipMemsetAsync(outdeg,  0, (size_t)N*4, stream);
  hipMemsetAsync(cursor,  0, (size_t)N*4, stream);
  hipMemsetAsync(node_sh, 0, (size_t)N*9*4, stream);
  hipMemsetAsync(mpool,   0, (size_t)NG*128*4, stream);
  hipMemsetAsync(cgp,     0, (size_t)NG*4, stream);

  const int TB = 256;
  const int gE = (E + TB - 1) / TB;
  const int gN = (N + TB - 1) / TB;
  const int gGA = (N + GA_NODES - 1) / GA_NODES;

  // CSR build + sh aggregation
  k_count<<<gE, TB, 0, stream>>>(esrc, edst, indeg, outdeg, E);
  k_prefix<<<1, 1024, 0, stream>>>(indeg, rowptr, N);
  k_fill<<<gE, TB, 0, stream>>>(esrc, edst, rowptr, cursor, csr_src, csr_dst, E);
  k_sh_scatter<<<gE, TB, 0, stream>>>(edge_vec, edst, node_sh, E);
  k_init_svd0<<<gN, TB, 0, stream>>>(x_scalars, node_sh, indeg, svd0, N);

  // ---- et0 layer (no residual) ----
  k_node_feats<10,1><<<gN, TB, 0, stream>>>(svd0, et0_W0, et0_W1, et0_W2, et0_Wd, qt, kf, vf, N);
  k_edge_logit2<<<gE, TB, 0, stream>>>(qt, kf, csr_src, csr_dst, elog, E);
  k_attn_gather<<<gGA, 576, 0, stream>>>(elog, vf, csr_src, rowptr, nullptr, stA, N);

  // ---- 2 hidden layers with residual ----
  float* cur = stA; float* oth = stB;
  for (int l = 0; l < 2; ++l) {
    k_node_feats<8,8><<<gN, TB, 0, stream>>>(cur, h_W0 + l*192, h_W1 + l*192,
                                             h_W2 + l*192, h_Wd + l*192, qt, kf, vf, N);
    k_edge_logit2<<<gE, TB, 0, stream>>>(qt, kf, csr_src, csr_dst, elog, E);
    k_attn_gather<<<gGA, 576, 0, stream>>>(elog, vf, csr_src, rowptr, cur, oth, N);
    float* t = cur; cur = oth; oth = t;
  }

  // ---- fused MLP head + group pooling ----
  k_head<<<N/16, 128, 0, stream>>>(cur, Wol, Wlin, blin, outdeg, bseg, mpool, cgp, N);
  k_out<<<1, 64, 0, stream>>>(mpool, cgp, Wout, bout, (float*)d_out);
}

// Round 3
// 802.826 us; speedup vs baseline: 4.7554x; 1.4570x over previous
//
#include <hip/hip_runtime.h>
#include <math.h>

#define NN 50000
#define NE 800000
#define NG 64

// ---- CSR build: count ----
__global__ void k_count(const int* __restrict__ esrc, const int* __restrict__ edst,
                        int* __restrict__ indeg, int* __restrict__ outdeg, int E)
{
  int e = blockIdx.x*blockDim.x + threadIdx.x;
  if (e >= E) return;
  atomicAdd(indeg + edst[e], 1);
  atomicAdd(outdeg + esrc[e], 1);
}

// ---- CSR build: single-block exclusive prefix scan over N=50000 ----
__global__ void __launch_bounds__(1024) k_prefix(const int* __restrict__ indeg,
                                                 int* __restrict__ rowptr, int N)
{
  __shared__ int tot[1024];
  int t = threadIdx.x;
  int chunk = (N + 1023) / 1024;
  int lo = t*chunk, hi = lo + chunk; if (hi > N) hi = N; if (lo > N) lo = N;
  int s = 0;
  for (int i = lo; i < hi; ++i) s += indeg[i];
  tot[t] = s;
  __syncthreads();
  for (int off = 1; off < 1024; off <<= 1) {
    int v = 0;
    if (t >= off) v = tot[t-off];
    __syncthreads();
    if (t >= off) tot[t] += v;
    __syncthreads();
  }
  int base = (t == 0) ? 0 : tot[t-1];
  for (int i = lo; i < hi; ++i) {
    rowptr[i] = base;
    base += indeg[i];
  }
  if (t == 1023) rowptr[N] = tot[1023];
}

// ---- CSR build: fill (slot order within a node is atomic-nondet; sums only) ----
__global__ void k_fill(const int* __restrict__ esrc, const int* __restrict__ edst,
                       const int* __restrict__ rowptr, int* __restrict__ cursor,
                       int* __restrict__ csr_src, int* __restrict__ csr_dst,
                       int* __restrict__ csr_eid, int E)
{
  int e = blockIdx.x*blockDim.x + threadIdx.x;
  if (e >= E) return;
  int d = edst[e];
  int slot = rowptr[d] + atomicAdd(cursor + d, 1);
  csr_src[slot] = esrc[e];
  csr_dst[slot] = d;
  csr_eid[slot] = e;
}

// ---- init: gather sh over CSR run + concat scalars -> svd0 [N,18] ----
__global__ void k_init_svd0(const float* __restrict__ xs,
                            const float* __restrict__ evec,
                            const int* __restrict__ csr_eid,
                            const int* __restrict__ rowptr,
                            float* __restrict__ svd0, int N)
{
  int n = blockIdx.x*blockDim.x + threadIdx.x;
  if (n >= N) return;
  int b = rowptr[n], e2 = rowptr[n+1];
  float acc[9];
  #pragma unroll
  for (int j = 0; j < 9; ++j) acc[j] = 0.f;
  const float s3  = 1.7320508075688772f;
  const float s15 = 3.872983346207417f;
  const float s5  = 2.23606797749979f;
  for (int s = b; s < e2; ++s) {
    int eid = csr_eid[s];
    float vx = evec[3*eid+0], vy = evec[3*eid+1], vz = evec[3*eid+2];
    float r = sqrtf(vx*vx + vy*vy + vz*vz + 1e-12f);
    float x = vx / r, y = vy / r, z = vz / r;
    acc[0] += 1.f;
    acc[1] += s3*x; acc[2] += s3*y; acc[3] += s3*z;
    acc[4] += s15*x*z;
    acc[5] += s15*x*y;
    acc[6] += s5*(y*y - 0.5f*(x*x + z*z));
    acc[7] += s15*y*z;
    acc[8] += 0.5f*s15*(z*z - x*x);
  }
  int dg = e2 - b;
  float inv = 1.f / (float)(dg > 1 ? dg : 1);
  float* o = svd0 + (size_t)n*18;
  const float* xrow = xs + (size_t)n*9;
  #pragma unroll
  for (int j = 0; j < 9; ++j) o[j] = xrow[j];
  #pragma unroll
  for (int j = 0; j < 9; ++j) o[9+j] = acc[j]*inv;
}

// ---- kernel A: node-level q/k/v features; q is pre-contracted with Wd ----
template<int CS, int CV>
__global__ void __launch_bounds__(256) k_node_feats(
    const float* __restrict__ in,
    const float* __restrict__ W0,  // [3,CS,8]
    const float* __restrict__ W1,  // [3,CV,8]
    const float* __restrict__ W2,  // [3,CV,8]
    const float* __restrict__ Wd,  // [3,8,8]
    float* __restrict__ qt,
    float* __restrict__ kf,
    float* __restrict__ vf,
    int N)
{
  int n = blockIdx.x*blockDim.x + threadIdx.x;
  if (n >= N) return;
  const float* x = in + (size_t)n*(CS + 8*CV);
  float s_in[CS];
  float v_in[CV][3];
  float d_in[CV][5];
  #pragma unroll
  for (int i = 0; i < CS; ++i) s_in[i] = x[i];
  #pragma unroll
  for (int i = 0; i < CV; ++i)
    #pragma unroll
    for (int m = 0; m < 3; ++m) v_in[i][m] = x[CS + i*3 + m];
  #pragma unroll
  for (int i = 0; i < CV; ++i)
    #pragma unroll
    for (int m = 0; m < 5; ++m) d_in[i][m] = x[CS + 3*CV + i*5 + m];

  const float inv_s3 = 0.5773502691896258f;
  const float inv_s5 = 0.4472135954999579f;

  #pragma unroll
  for (int t = 0; t < 3; ++t) {
    float ss[8];
    float vv[8][3];
    float dd[8][5];
    #pragma unroll
    for (int c = 0; c < 8; ++c) {
      float a = 0.f;
      #pragma unroll
      for (int i = 0; i < CS; ++i) a += s_in[i]*W0[t*CS*8 + i*8 + c];
      ss[c] = a;
    }
    #pragma unroll
    for (int c = 0; c < 8; ++c)
      #pragma unroll
      for (int m = 0; m < 3; ++m) {
        float a = 0.f;
        #pragma unroll
        for (int i = 0; i < CV; ++i) a += v_in[i][m]*W1[t*CV*8 + i*8 + c];
        vv[c][m] = a;
      }
    #pragma unroll
    for (int c = 0; c < 8; ++c)
      #pragma unroll
      for (int m = 0; m < 5; ++m) {
        float a = 0.f;
        #pragma unroll
        for (int i = 0; i < CV; ++i) a += d_in[i][m]*W2[t*CV*8 + i*8 + c];
        dd[c][m] = a;
      }

    if (t == 0) {
      float* q = qt + (size_t)n*72;
      #pragma unroll
      for (int dp = 0; dp < 8; ++dp) {
        float a = 0.f;
        #pragma unroll
        for (int c = 0; c < 8; ++c) a += ss[c]*Wd[0*64 + c*8 + dp];
        q[dp] = a;
      }
      #pragma unroll
      for (int dp = 0; dp < 8; ++dp)
        #pragma unroll
        for (int m = 0; m < 3; ++m) {
          float a = 0.f;
          #pragma unroll
          for (int c = 0; c < 8; ++c) a += vv[c][m]*Wd[1*64 + c*8 + dp];
          q[8 + dp*3 + m] = a*inv_s3;
        }
      #pragma unroll
      for (int dp = 0; dp < 8; ++dp)
        #pragma unroll
        for (int m = 0; m < 5; ++m) {
          float a = 0.f;
          #pragma unroll
          for (int c = 0; c < 8; ++c) a += dd[c][m]*Wd[2*64 + c*8 + dp];
          q[32 + dp*5 + m] = a*inv_s5;
        }
    } else {
      float* o = (t == 1 ? kf : vf) + (size_t)n*72;
      #pragma unroll
      for (int c = 0; c < 8; ++c) o[c] = ss[c];
      #pragma unroll
      for (int c = 0; c < 8; ++c)
        #pragma unroll
        for (int m = 0; m < 3; ++m) o[8 + c*3 + m] = vv[c][m];
      #pragma unroll
      for (int c = 0; c < 8; ++c)
        #pragma unroll
        for (int m = 0; m < 5; ++m) o[32 + c*5 + m] = dd[c][m];
    }
  }
}

// ---- kernel B: slot-parallel logit; dst-sorted so qt rows hit L1 ----
__global__ void k_edge_logit2(const float* __restrict__ qt,
                              const float* __restrict__ kf,
                              const int* __restrict__ csr_src,
                              const int* __restrict__ csr_dst,
                              float* __restrict__ elog, int E)
{
  int s = blockIdx.x*blockDim.x + threadIdx.x;
  if (s >= E) return;
  const float4* qa = (const float4*)(qt + (size_t)csr_dst[s]*72);
  const float4* kb = (const float4*)(kf + (size_t)csr_src[s]*72);
  float acc = 0.f;
  #pragma unroll
  for (int j = 0; j < 18; ++j) {
    float4 a = qa[j], b = kb[j];
    acc += a.x*b.x + a.y*b.y + a.z*b.z + a.w*b.w;
  }
  elog[s] = acc;
}

// ---- kernel D: per-node online softmax + weighted gather, 18 threads/node ----
#define GA_NODES 32
__global__ void __launch_bounds__(576) k_attn_gather(
    const float* __restrict__ elog,
    const float* __restrict__ vf,
    const int* __restrict__ csr_src,
    const int* __restrict__ rowptr,
    const float* __restrict__ base,   // residual input or nullptr
    float* __restrict__ out, int N)
{
  int t = threadIdx.x;
  int n = blockIdx.x*GA_NODES + t/18;
  int j = t - (t/18)*18;
  if (n >= N) return;
  int b = rowptr[n], e2 = rowptr[n+1];
  float ax = 0.f, ay = 0.f, az = 0.f, aw = 0.f;
  if (e2 > b) {
    // online softmax statistics (single pass)
    float mx = -3.4e38f, sum = 0.f;
    for (int s = b; s < e2; ++s) {
      float l = elog[s];
      float m2 = fmaxf(mx, l);
      sum = sum*expf(mx - m2) + expf(l - m2);
      mx = m2;
    }
    float inv = 1.f / sum;
    for (int s = b; s < e2; ++s) {
      float wv = sqrtf(expf(elog[s] - mx) * inv);
      const float4 v = *(const float4*)(vf + (size_t)csr_src[s]*72 + j*4);
      ax += wv*v.x; ay += wv*v.y; az += wv*v.z; aw += wv*v.w;
    }
  }
  if (base) {
    const float4 bb = *(const float4*)(base + (size_t)n*72 + j*4);
    ax += bb.x; ay += bb.y; az += bb.z; aw += bb.w;
  }
  float4 r; r.x = ax; r.y = ay; r.z = az; r.w = aw;
  *(float4*)(out + (size_t)n*72 + j*4) = r;
}

// ---- fused head: h=relu(L2norm(s@Wol)); 2x relu(h@W+b); group pooling ----
__global__ void __launch_bounds__(128) k_head(
    const float* __restrict__ svd,   // [N,72], s = first 8
    const float* __restrict__ Wol,   // [8,128]
    const float* __restrict__ Wlin,  // [2,128,128]
    const float* __restrict__ blin,  // [2,128]
    const int* __restrict__ outdeg,
    const int* __restrict__ bseg,
    float* __restrict__ m,           // [G,128] atomic
    float* __restrict__ cg,          // [G] atomic
    int N)
{
  __shared__ float hs[16][128];
  __shared__ float ssm[16][8];
  __shared__ float nrm[16];
  int c = threadIdx.x;
  int n0 = blockIdx.x*16;

  {
    int nn = c >> 3, i = c & 7;
    ssm[nn][i] = svd[(size_t)(n0+nn)*72 + i];
  }
  __syncthreads();

  float acc[16];
  #pragma unroll
  for (int nn = 0; nn < 16; ++nn) acc[nn] = 0.f;
  #pragma unroll
  for (int i = 0; i < 8; ++i) {
    float w = Wol[i*128 + c];
    #pragma unroll
    for (int nn = 0; nn < 16; ++nn) acc[nn] += ssm[nn][i]*w;
  }
  #pragma unroll
  for (int nn = 0; nn < 16; ++nn) hs[nn][c] = acc[nn];
  __syncthreads();
  if (c < 16) {
    float sq = 0.f;
    for (int i = 0; i < 128; ++i) { float h = hs[c][i]; sq += h*h; }
    nrm[c] = fmaxf(sqrtf(sq), 1e-12f);
  }
  __syncthreads();
  #pragma unroll
  for (int nn = 0; nn < 16; ++nn)
    hs[nn][c] = fmaxf(hs[nn][c] / nrm[nn], 0.f);
  __syncthreads();

  for (int l = 0; l < 2; ++l) {
    float b = blin[l*128 + c];
    float a2[16];
    #pragma unroll
    for (int nn = 0; nn < 16; ++nn) a2[nn] = b;
    for (int i = 0; i < 128; ++i) {
      float w = Wlin[l*16384 + i*128 + c];
      #pragma unroll
      for (int nn = 0; nn < 16; ++nn) a2[nn] += hs[nn][i]*w;
    }
    __syncthreads();
    #pragma unroll
    for (int nn = 0; nn < 16; ++nn) hs[nn][c] = fmaxf(a2[nn], 0.f);
    __syncthreads();
  }

  float accm = 0.f; int gprev = -1;
  for (int nn = 0; nn < 16; ++nn) {
    int n = n0 + nn;
    int g = bseg[n];
    if (g != gprev) {
      if (gprev >= 0) atomicAdd(&m[gprev*128 + c], accm);
      accm = 0.f; gprev = g;
    }
    accm += (float)outdeg[n]*hs[nn][c];
  }
  if (gprev >= 0) atomicAdd(&m[gprev*128 + c], accm);

  if (c == 0) {
    float a = 0.f; int gp = -1;
    for (int nn = 0; nn < 16; ++nn) {
      int n = n0 + nn;
      int g = bseg[n];
      if (g != gp) {
        if (gp >= 0) atomicAdd(&cg[gp], a);
        a = 0.f; gp = g;
      }
      a += (float)outdeg[n];
    }
    if (gp >= 0) atomicAdd(&cg[gp], a);
  }
}

// ---- final: softmax((m/cg) @ Wout + bout) ----
__global__ void k_out(const float* __restrict__ m, const float* __restrict__ cg,
                      const float* __restrict__ Wout, const float* __restrict__ bout,
                      float* __restrict__ out)
{
  int g = threadIdx.x;
  if (g >= NG) return;
  float inv = 1.f / fmaxf(cg[g], 1.f);
  float v[9];
  #pragma unroll
  for (int j = 0; j < 9; ++j) {
    float a = 0.f;
    for (int i = 0; i < 128; ++i) a += m[g*128 + i]*Wout[i*9 + j];
    v[j] = a*inv + bout[j];
  }
  float mxv = v[0];
  #pragma unroll
  for (int j = 1; j < 9; ++j) mxv = fmaxf(mxv, v[j]);
  float sum = 0.f;
  #pragma unroll
  for (int j = 0; j < 9; ++j) { v[j] = expf(v[j] - mxv); sum += v[j]; }
  #pragma unroll
  for (int j = 0; j < 9; ++j) out[g*9 + j] = v[j]/sum;
}

extern "C" void kernel_launch(void* const* d_in, const int* in_sizes, int n_in,
                              void* d_out, int out_size, void* d_ws, size_t ws_size,
                              hipStream_t stream) {
  (void)in_sizes; (void)n_in; (void)out_size; (void)ws_size;
  const float* x_scalars = (const float*)d_in[0];
  const float* edge_vec  = (const float*)d_in[1];
  const float* et0_W0    = (const float*)d_in[2];
  const float* et0_W1    = (const float*)d_in[3];
  const float* et0_W2    = (const float*)d_in[4];
  const float* et0_Wd    = (const float*)d_in[5];
  const float* h_W0      = (const float*)d_in[6];
  const float* h_W1      = (const float*)d_in[7];
  const float* h_W2      = (const float*)d_in[8];
  const float* h_Wd      = (const float*)d_in[9];
  const float* Wol       = (const float*)d_in[10];
  const float* Wlin      = (const float*)d_in[11];
  const float* blin      = (const float*)d_in[12];
  const float* Wout      = (const float*)d_in[13];
  const float* bout      = (const float*)d_in[14];
  const int*   esrc      = (const int*)d_in[15];
  const int*   edst      = (const int*)d_in[16];
  const int*   bseg      = (const int*)d_in[17];

  const int N = NN, E = NE;

  char* w = (char*)d_ws;
  auto alloc = [&](size_t nbytes) {
    char* p = w;
    w += (nbytes + 255) & ~(size_t)255;
    return p;
  };
  int*   indeg   = (int*)  alloc((size_t)N*4);
  int*   outdeg  = (int*)  alloc((size_t)N*4);
  int*   cursor  = (int*)  alloc((size_t)N*4);
  int*   rowptr  = (int*)  alloc((size_t)(N+1)*4);
  int*   csr_src = (int*)  alloc((size_t)E*4);
  int*   csr_dst = (int*)  alloc((size_t)E*4);
  int*   csr_eid = (int*)  alloc((size_t)E*4);
  float* svd0    = (float*)alloc((size_t)N*18*4);
  float* stA     = (float*)alloc((size_t)N*72*4);
  float* stB     = (float*)alloc((size_t)N*72*4);
  float* qt      = (float*)alloc((size_t)N*72*4);
  float* kf      = (float*)alloc((size_t)N*72*4);
  float* vf      = (float*)alloc((size_t)N*72*4);
  float* elog    = (float*)alloc((size_t)E*4);
  float* mpool   = (float*)alloc((size_t)NG*128*4);
  float* cgp     = (float*)alloc((size_t)NG*4);

  hipMemsetAsync(indeg,   0, (size_t)N*4, stream);
  hipMemsetAsync(outdeg,  0, (size_t)N*4, stream);
  hipMemsetAsync(cursor,  0, (size_t)N*4, stream);
  hipMemsetAsync(mpool,   0, (size_t)NG*128*4, stream);
  hipMemsetAsync(cgp,     0, (size_t)NG*4, stream);

  const int TB = 256;
  const int gE = (E + TB - 1) / TB;
  const int gN = (N + TB - 1) / TB;
  const int gGA = (N + GA_NODES - 1) / GA_NODES;

  // CSR build, then sh gather + init
  k_count<<<gE, TB, 0, stream>>>(esrc, edst, indeg, outdeg, E);
  k_prefix<<<1, 1024, 0, stream>>>(indeg, rowptr, N);
  k_fill<<<gE, TB, 0, stream>>>(esrc, edst, rowptr, cursor, csr_src, csr_dst, csr_eid, E);
  k_init_svd0<<<gN, TB, 0, stream>>>(x_scalars, edge_vec, csr_eid, rowptr, svd0, N);

  // ---- et0 layer (no residual) ----
  k_node_feats<10,1><<<gN, TB, 0, stream>>>(svd0, et0_W0, et0_W1, et0_W2, et0_Wd, qt, kf, vf, N);
  k_edge_logit2<<<gE, TB, 0, stream>>>(qt, kf, csr_src, csr_dst, elog, E);
  k_attn_gather<<<gGA, 576, 0, stream>>>(elog, vf, csr_src, rowptr, nullptr, stA, N);

  // ---- 2 hidden layers with residual ----
  float* cur = stA; float* oth = stB;
  for (int l = 0; l < 2; ++l) {
    k_node_feats<8,8><<<gN, TB, 0, stream>>>(cur, h_W0 + l*192, h_W1 + l*192,
                                             h_W2 + l*192, h_Wd + l*192, qt, kf, vf, N);
    k_edge_logit2<<<gE, TB, 0, stream>>>(qt, kf, csr_src, csr_dst, elog, E);
    k_attn_gather<<<gGA, 576, 0, stream>>>(elog, vf, csr_src, rowptr, cur, oth, N);
    float* t = cur; cur = oth; oth = t;
  }

  // ---- fused MLP head + group pooling ----
  k_head<<<N/16, 128, 0, stream>>>(cur, Wol, Wlin, blin, outdeg, bseg, mpool, cgp, N);
  k_out<<<1, 64, 0, stream>>>(mpool, cgp, Wout, bout, (float*)d_out);
}